// Round 6
// baseline (647.528 us; speedup 1.0000x reference)
//
#include <hip/hip_runtime.h>
#include <hip/hip_bf16.h>

using f32x4 = __attribute__((ext_vector_type(4))) float;
using s16x8 = __attribute__((ext_vector_type(8))) short;

#define DEVFN static __device__ __forceinline__

static constexpr int NCOL = 256;
static constexpr int MROWS = 8192;
static constexpr int BM = 64;             // 4 waves x 16 rows
static constexpr int THREADS = 256;
static constexpr int NTILE = MROWS / BM;  // 128

DEVFN unsigned short f2bf(float f) {
  union { float f; unsigned u; } x; x.f = f;
  unsigned u = x.u;
  u += 0x7fffu + ((u >> 16) & 1u);   // RNE
  return (unsigned short)(u >> 16);
}

DEVFN s16x8 pack8(f32x4 v0, f32x4 v1) {
  union { s16x8 v; unsigned short u[8]; } pk;
  pk.u[0] = f2bf(v0[0]); pk.u[1] = f2bf(v0[1]);
  pk.u[2] = f2bf(v0[2]); pk.u[3] = f2bf(v0[3]);
  pk.u[4] = f2bf(v1[0]); pk.u[5] = f2bf(v1[1]);
  pk.u[6] = f2bf(v1[2]); pk.u[7] = f2bf(v1[3]);
  return pk.v;
}

// C[M,256] = A[M,K] @ B[K,256], barrier-free / LDS-free.
//  Each wave independently computes 16 rows x 256 cols of its k-slice.
//  A f32 row-major -> regs -> bf16 (packed once per element per wave).
//  B bf16 in P8 layout: elem (k,j) at ((k>>3)*256 + j)*8 + (k&7); fragments
//  are 16B-contiguous, loaded global->reg through L1/L2 (panel is L2-hot),
//  4-slot register pipeline, 2 groups ahead. Compiler inserts exact vmcnt.
//  KS-way split-K. EPI 0: f32 partials Cpart[kh][M][256]. EPI 1 (KS==1):
//  direct P8 bf16 output.
template<int KS, int EPI>
__global__ __launch_bounds__(THREADS, 2)
void gemm_ws(const float* __restrict__ A, int Kfull,
             const unsigned short* __restrict__ Bp8,
             float* __restrict__ Cpart, unsigned short* __restrict__ Pout)
{
  const int nwg = NTILE * KS;
  const int q = nwg / 8;
  const int logical = (blockIdx.x & 7) * q + (blockIdx.x >> 3);  // XCD-chunked
  const int kh = logical / NTILE;
  const int tile = logical % NTILE;

  const int klen = Kfull / KS;
  const int nt = klen / 64;            // K-step = 64 (two k=32 MFMA halves)
  const int k0 = kh * klen;
  const int tid = threadIdx.x;
  const int lane = tid & 63;
  const int wave = tid >> 6;
  const int lr = lane & 15, lg = lane >> 4;

  // per-lane A source: row tile*64 + wave*16 + lr, k chunk lg*8
  const float* Ap = A + (size_t)(tile * BM + wave * 16 + lr) * Kfull + k0 + lg * 8;
  // per-lane B base (shorts): ((k0/8 + lg)*256)*8
  const unsigned short* Bk = Bp8 + ((size_t)(k0 >> 3) + lg) * 2048;

  auto lda = [&](int t, f32x4* r) {
    const float* p = Ap + t * 64;
    r[0] = ((const f32x4*)p)[0];
    r[1] = ((const f32x4*)p)[1];
    r[2] = ((const f32x4*)(p + 32))[0];
    r[3] = ((const f32x4*)(p + 32))[1];
  };
  auto ldb = [&](int t, int kh2, int cq, s16x8* d) {
    const unsigned short* p = Bk + (size_t)(t * 8 + kh2 * 4) * 2048 + (cq * 64 + lr) * 8;
#pragma unroll
    for (int fn = 0; fn < 4; ++fn)
      d[fn] = *(const s16x8*)(p + fn * 128);
  };

  f32x4 acc[4][4] = {};
  s16x8 bs[4][4];            // 4 rotating slots x 4 col-fragments
  f32x4 ra[4];
  s16x8 a0, a1;

  // prologue
  lda(0, ra);
  a0 = pack8(ra[0], ra[1]); a1 = pack8(ra[2], ra[3]);
  ldb(0, 0, 0, bs[0]);       // item 0 -> slot 0
  ldb(0, 0, 1, bs[1]);       // item 1 -> slot 1

  for (int t = 0; t < nt; ++t) {
    if (t + 1 < nt) lda(t + 1, ra);
#pragma unroll
    for (int g = 0; g < 8; ++g) {                 // item i = t*8+g, slot i&3
      const int g2 = (g + 2) & 7;                 // issue item i+2
      const int tn = t + (g >= 6);
      if (g < 6 || t + 1 < nt)
        ldb(tn, g2 >> 2, g2 & 3, bs[(g + 2) & 3]);
      const s16x8 af = (g >> 2) ? a1 : a0;
      const int cq = g & 3;
#pragma unroll
      for (int fn = 0; fn < 4; ++fn)
        acc[cq][fn] = __builtin_amdgcn_mfma_f32_16x16x32_bf16(
            af, bs[g & 3][fn], acc[cq][fn], 0, 0, 0);
    }
    if (t + 1 < nt) { a0 = pack8(ra[0], ra[1]); a1 = pack8(ra[2], ra[3]); }
  }

  // C/D layout: col = lane&15, row = (lane>>4)*4 + reg
  const int r0 = tile * BM + wave * 16 + lg * 4;
  if constexpr (EPI == 0) {
    float* Co = Cpart + (size_t)kh * MROWS * NCOL;
#pragma unroll
    for (int cq = 0; cq < 4; ++cq)
#pragma unroll
      for (int fn = 0; fn < 4; ++fn) {
        const int col = cq * 64 + fn * 16 + lr;
#pragma unroll
        for (int r = 0; r < 4; ++r)
          Co[(size_t)(r0 + r) * NCOL + col] = acc[cq][fn][r];
      }
  } else {
#pragma unroll
    for (int cq = 0; cq < 4; ++cq)
#pragma unroll
      for (int fn = 0; fn < 4; ++fn) {
        const int col = cq * 64 + fn * 16 + lr;
        ushort4 u;
        u.x = f2bf(acc[cq][fn][0]); u.y = f2bf(acc[cq][fn][1]);
        u.z = f2bf(acc[cq][fn][2]); u.w = f2bf(acc[cq][fn][3]);
        *(ushort4*)&Pout[((size_t)(r0 >> 3) * 256 + col) * 8 + (r0 & 7)] = u;
      }
  }
}

// ---- small conversion / reduce kernels ---------------------------------

// f32 [K][256] -> P8 bf16
__global__ void k_convert_p8(const float* __restrict__ W, int K,
                             unsigned short* __restrict__ outp) {
  int tid = blockIdx.x * blockDim.x + threadIdx.x;
  if (tid >= K * NCOL / 4) return;
  int j = tid & (NCOL - 1);
  int i0 = (tid >> 8) << 2;
  unsigned short u[4];
#pragma unroll
  for (int r = 0; r < 4; ++r) u[r] = f2bf(W[(size_t)(i0 + r) * NCOL + j]);
  size_t off = ((size_t)(i0 >> 3) * NCOL + j) * 8 + (i0 & 7);
  *(ushort4*)&outp[off] = make_ushort4(u[0], u[1], u[2], u[3]);
}

// sum 4 partials, optional per-row filter scale, write P8 bf16
__global__ void k_reduce_p8(const float* __restrict__ P, const float* __restrict__ filt,
                            unsigned short* __restrict__ outp) {
  int tid = blockIdx.x * blockDim.x + threadIdx.x;
  int j = tid & (NCOL - 1);
  int i0 = (tid >> 8) << 2;
  unsigned short u[4];
#pragma unroll
  for (int r = 0; r < 4; ++r) {
    size_t o = (size_t)(i0 + r) * NCOL + j;
    float v = P[o] + P[(size_t)MROWS * NCOL + o]
            + P[2 * (size_t)MROWS * NCOL + o] + P[3 * (size_t)MROWS * NCOL + o];
    if (filt) v *= filt[i0 + r];
    u[r] = f2bf(v);
  }
  size_t off = ((size_t)(i0 >> 3) * NCOL + j) * 8 + (i0 & 7);
  *(ushort4*)&outp[off] = make_ushort4(u[0], u[1], u[2], u[3]);
}

// sum 4 partials, relu, write row-major f32 (A operand of next GEMM)
__global__ void k_reduce_relu(const float* __restrict__ P, float* __restrict__ h1f) {
  size_t o = (size_t)(blockIdx.x * blockDim.x + threadIdx.x) * 4;
  float4 a = *(const float4*)&P[o];
  float4 b = *(const float4*)&P[(size_t)MROWS * NCOL + o];
  float4 c = *(const float4*)&P[2 * (size_t)MROWS * NCOL + o];
  float4 d = *(const float4*)&P[3 * (size_t)MROWS * NCOL + o];
  float4 v;
  v.x = fmaxf(a.x + b.x + c.x + d.x, 0.f);
  v.y = fmaxf(a.y + b.y + c.y + d.y, 0.f);
  v.z = fmaxf(a.z + b.z + c.z + d.z, 0.f);
  v.w = fmaxf(a.w + b.w + c.w + d.w, 0.f);
  *(float4*)&h1f[o] = v;
}

// sum 4 partials, write f32 (final output)
__global__ void k_reduce_f32(const float* __restrict__ P, float* __restrict__ out) {
  size_t o = (size_t)(blockIdx.x * blockDim.x + threadIdx.x) * 4;
  float4 a = *(const float4*)&P[o];
  float4 b = *(const float4*)&P[(size_t)MROWS * NCOL + o];
  float4 c = *(const float4*)&P[2 * (size_t)MROWS * NCOL + o];
  float4 d = *(const float4*)&P[3 * (size_t)MROWS * NCOL + o];
  float4 v; v.x = a.x + b.x + c.x + d.x; v.y = a.y + b.y + c.y + d.y;
  v.z = a.z + b.z + c.z + d.z; v.w = a.w + b.w + c.w + d.w;
  *(float4*)&out[o] = v;
}

extern "C" void kernel_launch(void* const* d_in, const int* in_sizes, int n_in,
                              void* d_out, int out_size, void* d_ws, size_t ws_size,
                              hipStream_t stream) {
  const float* input = (const float*)d_in[0];
  const float* Wv    = (const float*)d_in[1];
  const float* Winv  = (const float*)d_in[2];
  const float* W1    = (const float*)d_in[3];
  const float* W2    = (const float*)d_in[4];
  const float* f1    = (const float*)d_in[5];
  const float* f2    = (const float*)d_in[6];
  float* out = (float*)d_out;

  char* ws = (char*)d_ws;
  float* part         = (float*)(ws);                         // 32MB
  unsigned short* t1p = (unsigned short*)(ws + 0x2000000);    // 4MB each, P8
  unsigned short* s1p = (unsigned short*)(ws + 0x2400000);
  unsigned short* t2p = (unsigned short*)(ws + 0x2800000);
  unsigned short* s2p = (unsigned short*)(ws + 0x2C00000);
  float* h1f          = (float*)(ws + 0x3000000);             // 8MB f32
  unsigned short* W1p = (unsigned short*)(ws + 0x3800000);    // 256KB
  unsigned short* W2p = (unsigned short*)(ws + 0x3840000);    // 128KB

  dim3 gT(THREADS);
  dim3 gBig(NTILE * 4);                                // 512 WGs, 2/CU
  dim3 gSmall(NTILE);                                  // 128 WGs
  dim3 rT(256), rG(MROWS * NCOL / 4 / 256);            // 2048 WGs

  k_convert_p8<<<dim3(128), rT, 0, stream>>>(W1, 512, W1p);
  k_convert_p8<<<dim3(64),  rT, 0, stream>>>(W2, 256, W2p);

  // t1 = input @ W1                       (KS=1, direct P8 out)
  gemm_ws<1, 1><<<gSmall, gT, 0, stream>>>(input, 512, W1p, nullptr, t1p);
  // s1 = diag(f1).(Winv @ t1)
  gemm_ws<4, 0><<<gBig, gT, 0, stream>>>(Winv, 8192, t1p, part, nullptr);
  k_reduce_p8<<<rG, rT, 0, stream>>>(part, f1, s1p);
  // h1 = relu(Wv @ s1), f32
  gemm_ws<4, 0><<<gBig, gT, 0, stream>>>(Wv, 8192, s1p, part, nullptr);
  k_reduce_relu<<<rG, rT, 0, stream>>>(part, h1f);
  // t2 = h1 @ W2                          (KS=1, direct P8 out)
  gemm_ws<1, 1><<<gSmall, gT, 0, stream>>>(h1f, 256, W2p, nullptr, t2p);
  // s2 = diag(f2).(Winv @ t2)
  gemm_ws<4, 0><<<gBig, gT, 0, stream>>>(Winv, 8192, t2p, part, nullptr);
  k_reduce_p8<<<rG, rT, 0, stream>>>(part, f2, s2p);
  // out = Wv @ s2, f32
  gemm_ws<4, 0><<<gBig, gT, 0, stream>>>(Wv, 8192, s2p, part, nullptr);
  k_reduce_f32<<<rG, rT, 0, stream>>>(part, out);
}